// Round 1
// baseline (617.959 us; speedup 1.0000x reference)
//
#include <hip/hip_runtime.h>

// Problem constants
#define NW    8192
#define MAXW  20
#define BB    64
#define SS    256
#define CHS   128
#define CHE   64
#define HH    256
#define G3    768
#define WEM   300
#define CAPEM 16

typedef _Float16 half8  __attribute__((ext_vector_type(8)));
typedef _Float16 half4v __attribute__((ext_vector_type(4)));
typedef float    f32x4  __attribute__((ext_vector_type(4)));

// workspace layout (bytes)
#define WF_OFF  0                        // f16 w_hh, 2 dirs: 2*768*256*2 = 786432
#define GI_OFF  (2*G3*HH*2)              // f32 gi table, 2 dirs: 2*128*768*4 = 786432
#define EMS_OFF (GI_OFF + 2*CHS*G3*4)    // f32 ems, 2 dirs: 2*8192*256*4 = 16777216
// total ~17.5 MB

__device__ __forceinline__ float fast_sigmoid(float x) {
    float e = __builtin_amdgcn_exp2f(-1.442695041f * x);
    return __builtin_amdgcn_rcpf(1.0f + e);
}
__device__ __forceinline__ float fast_tanh(float x) {
    float e = __builtin_amdgcn_exp2f(2.885390082f * x);
    return 1.0f - 2.0f * __builtin_amdgcn_rcpf(1.0f + e);
}

// Cast w_hh to f16, both dirs. grid 2*768 blocks x 256 thr.
__global__ void prep_w(const float* __restrict__ fw_whh, const float* __restrict__ bw_whh,
                       _Float16* __restrict__ Wf) {
    int bx = blockIdx.x;
    int dir = (bx >= G3) ? 1 : 0;
    int m = bx - dir * G3;
    int k = threadIdx.x;                       // 0..255
    const float* src = dir ? bw_whh : fw_whh;
    Wf[dir * G3 * HH + m * HH + k] = (_Float16)src[m * HH + k];
}

// gi table: gi[dir][c][j] = sum_e w_ih[j][e]*ch_em[c][e] + b_ih[j] + (j<512 ? b_hh[j] : 0)
// grid 256 blocks (dir*128 + c) x 256 thr, each thread does 3 j's.
__global__ void prep_gi(const float* __restrict__ ch_em,
                        const float* __restrict__ fw_wih, const float* __restrict__ fw_bih,
                        const float* __restrict__ fw_bhh,
                        const float* __restrict__ bw_wih, const float* __restrict__ bw_bih,
                        const float* __restrict__ bw_bhh,
                        float* __restrict__ gi) {
    int bx = blockIdx.x;
    int dir = bx >> 7;
    int c = bx & 127;
    const float* wih = dir ? bw_wih : fw_wih;
    const float* bih = dir ? bw_bih : fw_bih;
    const float* bhh = dir ? bw_bhh : fw_bhh;
    const float* ce = ch_em + c * CHE;
    for (int jj = 0; jj < 3; ++jj) {
        int j = jj * 256 + threadIdx.x;
        float s = bih[j] + (j < 512 ? bhh[j] : 0.0f);
        const float* wr = wih + j * CHE;
        #pragma unroll
        for (int e = 0; e < CHE; ++e) s += wr[e] * ce[e];
        gi[dir * CHS * G3 + c * G3 + j] = s;
    }
}

// GRU: 256 blocks (dir*128 + word-block) x 512 thr (8 waves).
// Per block: 64 words, 20 steps. C = W_hh[768,256] x h^T[256,64] via mfma 16x16x32 f16.
// acc init = gi (r,z gates); h kept f32 in regs, shared as f16 via LDS.
__global__ __launch_bounds__(512, 2)
void gru(const int* __restrict__ ch, const int* __restrict__ rev_ch,
         const int* __restrict__ wlen,
         const float* __restrict__ fw_bhh, const float* __restrict__ bw_bhh,
         const _Float16* __restrict__ Wf, const float* __restrict__ gi,
         float* __restrict__ ems) {
    int dir = blockIdx.x >> 7;
    int wblk = blockIdx.x & 127;
    int w0 = wblk * 64;
    const int* chp = dir ? rev_ch : ch;
    const _Float16* W = Wf + dir * G3 * HH;
    const float* gt = gi + dir * CHS * G3;
    const float* bh = dir ? bw_bhh : fw_bhh;
    float* emsd = ems + dir * NW * HH;

    int tid = threadIdx.x;
    int cg = tid >> 6;          // col-group 0..7 -> h cols [cg*32, cg*32+32)
    int lane = tid & 63;
    int q = lane >> 4;          // 0..3
    int l16 = lane & 15;

    __shared__ __align__(16) _Float16 hbuf[64][264];   // [word][k], +8 pad (2-way banks)
    for (int i = tid; i < 64 * 264; i += 512) ((_Float16*)hbuf)[i] = (_Float16)0.0f;

    int wl[4]; int widx[4];
    #pragma unroll
    for (int ct = 0; ct < 4; ++ct) {
        widx[ct] = w0 + ct * 16 + l16;
        wl[ct] = wlen[widx[ct]];
    }

    f32x4 bhhn[2];
    #pragma unroll
    for (int rt = 0; rt < 2; ++rt)
        bhhn[rt] = *(const f32x4*)(bh + 512 + cg * 32 + rt * 16 + q * 4);

    const f32x4 fz = {0.0f, 0.0f, 0.0f, 0.0f};
    f32x4 hprev[2][4];
    #pragma unroll
    for (int rt = 0; rt < 2; ++rt)
        #pragma unroll
        for (int ct = 0; ct < 4; ++ct) hprev[rt][ct] = fz;

    __syncthreads();

    for (int t = 0; t < MAXW; ++t) {
        // this step's chars (per owned word)
        int c4[4];
        #pragma unroll
        for (int ct = 0; ct < 4; ++ct) c4[ct] = chp[widx[ct] * MAXW + t];

        // acc init: r,z gates get gi directly (C-operand); n gate zero, i_n held aside
        f32x4 acc[3][2][4];
        f32x4 gin[2][4];
        #pragma unroll
        for (int ct = 0; ct < 4; ++ct) {
            const float* gr = gt + c4[ct] * G3 + cg * 32 + q * 4;
            #pragma unroll
            for (int rt = 0; rt < 2; ++rt) {
                acc[0][rt][ct] = *(const f32x4*)(gr + rt * 16);
                acc[1][rt][ct] = *(const f32x4*)(gr + 256 + rt * 16);
                acc[2][rt][ct] = fz;
                gin[rt][ct]    = *(const f32x4*)(gr + 512 + rt * 16);
            }
        }

        // MFMA: K = 256 in 8 k-tiles of 32
        #pragma unroll
        for (int kk = 0; kk < 8; ++kk) {
            half8 af[3][2];
            #pragma unroll
            for (int g = 0; g < 3; ++g)
                #pragma unroll
                for (int rt = 0; rt < 2; ++rt) {
                    int m = g * 256 + cg * 32 + rt * 16 + l16;
                    af[g][rt] = *(const half8*)(W + m * HH + kk * 32 + q * 8);
                }
            #pragma unroll
            for (int ct = 0; ct < 4; ++ct) {
                half8 bf = *(const half8*)(&hbuf[ct * 16 + l16][kk * 32 + q * 8]);
                #pragma unroll
                for (int g = 0; g < 3; ++g)
                    #pragma unroll
                    for (int rt = 0; rt < 2; ++rt)
                        acc[g][rt][ct] = __builtin_amdgcn_mfma_f32_16x16x32_f16(
                            af[g][rt], bf, acc[g][rt][ct], 0, 0, 0);
            }
        }

        __syncthreads();   // all waves done reading hbuf(t-1)

        // elementwise gates + h update + LDS/global writeback
        #pragma unroll
        for (int ct = 0; ct < 4; ++ct) {
            int word = ct * 16 + l16;
            #pragma unroll
            for (int rt = 0; rt < 2; ++rt) {
                f32x4 hv = hprev[rt][ct];
                f32x4 out4;
                half4v hh4;
                #pragma unroll
                for (int e = 0; e < 4; ++e) {
                    float r  = fast_sigmoid(acc[0][rt][ct][e]);
                    float z  = fast_sigmoid(acc[1][rt][ct][e]);
                    float hn = acc[2][rt][ct][e] + bhhn[rt][e];
                    float n  = fast_tanh(gin[rt][ct][e] + r * hn);
                    float hnew = n + z * (hv[e] - n);
                    out4[e] = hnew;
                    hh4[e] = (_Float16)hnew;
                }
                hprev[rt][ct] = out4;
                int colb = cg * 32 + rt * 16 + q * 4;
                *(half4v*)(&hbuf[word][colb]) = hh4;
                if (t + 1 == wl[ct])
                    *(f32x4*)(emsd + (size_t)widx[ct] * HH + colb) = out4;
            }
        }
        __syncthreads();   // hbuf(t) complete before next step's reads
    }
}

// Gather/concat: one block per (b,s) position; 828 f32 out each.
__global__ void emit(const int* __restrict__ w, const int* __restrict__ wcap,
                     const int* __restrict__ wchs, const float* __restrict__ wmask,
                     const float* __restrict__ w_em, const float* __restrict__ cap_em,
                     const float* __restrict__ ems, float* __restrict__ out) {
    int pos = blockIdx.x;
    int tid = threadIdx.x;
    int wi = w[pos], cap = wcap[pos], wch = wchs[pos];
    float m = wmask[pos];
    const float* suf = ems + (size_t)wch * HH;             // dir0 = fw = suffix
    const float* pre = ems + (size_t)NW * HH + (size_t)wch * HH;  // dir1 = bw = prefix
    float* o = out + (size_t)pos * 828;
    o[tid] = pre[tid] * m;
    for (int j = tid; j < WEM; j += 256) o[256 + j] = w_em[(size_t)wi * WEM + j];
    o[556 + tid] = suf[tid] * m;
    if (tid < CAPEM) o[812 + tid] = cap_em[cap * CAPEM + tid];
}

extern "C" void kernel_launch(void* const* d_in, const int* in_sizes, int n_in,
                              void* d_out, int out_size, void* d_ws, size_t ws_size,
                              hipStream_t stream) {
    const int*   ch      = (const int*)d_in[0];
    const int*   rev_ch  = (const int*)d_in[1];
    const int*   w_len   = (const int*)d_in[2];
    const int*   w       = (const int*)d_in[3];
    const int*   w_cap   = (const int*)d_in[4];
    const int*   w_chs   = (const int*)d_in[5];
    const float* w_mask  = (const float*)d_in[6];
    const float* ch_em   = (const float*)d_in[7];
    const float* w_em    = (const float*)d_in[8];
    const float* cap_em  = (const float*)d_in[9];
    const float* fw_wih  = (const float*)d_in[10];
    const float* fw_whh  = (const float*)d_in[11];
    const float* fw_bih  = (const float*)d_in[12];
    const float* fw_bhh  = (const float*)d_in[13];
    const float* bw_wih  = (const float*)d_in[14];
    const float* bw_whh  = (const float*)d_in[15];
    const float* bw_bih  = (const float*)d_in[16];
    const float* bw_bhh  = (const float*)d_in[17];

    char* ws = (char*)d_ws;
    _Float16* Wf = (_Float16*)(ws + WF_OFF);
    float* gi  = (float*)(ws + GI_OFF);
    float* ems = (float*)(ws + EMS_OFF);
    float* out = (float*)d_out;

    prep_w <<<2 * G3, 256, 0, stream>>>(fw_whh, bw_whh, Wf);
    prep_gi<<<256, 256, 0, stream>>>(ch_em, fw_wih, fw_bih, fw_bhh,
                                     bw_wih, bw_bih, bw_bhh, gi);
    gru    <<<256, 512, 0, stream>>>(ch, rev_ch, w_len, fw_bhh, bw_bhh, Wf, gi, ems);
    emit   <<<BB * SS, 256, 0, stream>>>(w, w_cap, w_chs, w_mask, w_em, cap_em, ems, out);
}